// Round 15
// baseline (213.110 us; speedup 1.0000x reference)
//
#include <hip/hip_runtime.h>
#include <math.h>

#define NB  32
#define TDS 2048
#define LL  512
#define DD  256
#define DC  64   // D/RATIO
#define GAP_THR 4e-4f

typedef __attribute__((ext_vector_type(8)))  short short8;
typedef __attribute__((ext_vector_type(16))) float f32x16;
typedef __attribute__((ext_vector_type(4)))  float f32x4;

__device__ __forceinline__ unsigned short f2bf(float x) {
    union { float f; unsigned u; } v; v.f = x;
    unsigned r = v.u + 0x7fffu + ((v.u >> 16) & 1u);
    return (unsigned short)(r >> 16);
}
__device__ __forceinline__ float bf2f(unsigned short h) {
    union { unsigned u; float f; } v; v.u = ((unsigned)h) << 16;
    return v.f;
}
// range-reduced sincos: f64 reduction to [-pi,pi], f32 evaluation (~1e-7 abs err)
__device__ __forceinline__ void rr_sincosf(double ang, float* s, float* c) {
    double n = rint(ang * 0.15915494309189535);
    double red = fma(n, -6.283185307179586, ang);
    sincosf((float)red, s, c);
}

// ---------------------------------------------------------------------------
// ws layout (bytes):
//   [0, 16777216)           : KPS  bf16 hi+lo of k+pe_k, MFMA-fragment order
//   [16777216, 18874368)    : PEQ  f32 (pe_q with w_s=1)
//   then NB*TDS ints IDX, 1 int CNT, NB*TDS ints FLAGS
// KPS fragment order: element (b, l=cs*32+lane32, k=ks*32+kh*16+g*8+j, plane):
//   byte = b*524288 + ks*65536 + cs*4096 + plane*2048 + kh*1024 + g*512
//        + lane32*16 + j*2
// ---------------------------------------------------------------------------

// merged table builder: blocks [0,2048) build PEQ (+cnt init);
// blocks [2048,4096) build the KPS fragment image.
__global__ __launch_bounds__(256)
void tables_kernel(const float* __restrict__ k,
                   const int* __restrict__ text_lengths,
                   const int* __restrict__ mel_lengths,
                   float* __restrict__ peq,
                   char* __restrict__ kps,
                   int* __restrict__ cnt) {
    const int tid = threadIdx.x;
    if (blockIdx.x < 2048) {
        int idx = blockIdx.x * 256 + tid;            // < TDS*DD
        if (idx == 0) cnt[0] = 0;
        int t = idx >> 8;
        int d = idx & 255;
        int i = d >> 1;
        double invd = exp((double)i * (-9.210340371976184 / 128.0));
        double ang = (double)t * invd;
        double s, c;
        sincos(ang, &s, &c);
        peq[idx] = (float)((d & 1) ? c : s);
        return;
    }
    __shared__ double invdiv[128];
    if (tid < 128) invdiv[tid] = exp((double)tid * (-9.210340371976184 / 128.0));
    __syncthreads();
    int f = (blockIdx.x - 2048) * 256 + tid;         // < NB*16384
    int b = f >> 14;
    int r = f & 16383;
    int ks = r >> 11;                                // 0..7
    int r2 = r & 2047;
    int cs = r2 >> 7;                                // 0..15
    int r3 = r2 & 127;
    int kh = r3 >> 6;
    int g  = (r3 >> 5) & 1;
    int lane32 = r3 & 31;
    int l  = cs * 32 + lane32;
    int k0 = ks * 32 + kh * 16 + g * 8;
    const float* kr = k + ((size_t)(b * LL + l)) * DD + k0;
    float4 kv0 = *(const float4*)(kr);
    float4 kv1 = *(const float4*)(kr + 4);
    float kv[8] = {kv0.x, kv0.y, kv0.z, kv0.w, kv1.x, kv1.y, kv1.z, kv1.w};
    double wsd = ((double)mel_lengths[b] * 0.25) / (double)text_lengths[b];
    double base_ang = wsd * (double)l;
    unsigned short h[8], lo8[8];
#pragma unroll
    for (int jj = 0; jj < 4; ++jj) {
        int i = (k0 >> 1) + jj;
        float sn, cs2;
        rr_sincosf(base_ang * invdiv[i], &sn, &cs2);
        float e0 = kv[2 * jj] + sn;
        float e1 = kv[2 * jj + 1] + cs2;
        h[2 * jj]       = f2bf(e0);
        h[2 * jj + 1]   = f2bf(e1);
        lo8[2 * jj]     = f2bf(e0 - bf2f(h[2 * jj]));
        lo8[2 * jj + 1] = f2bf(e1 - bf2f(h[2 * jj + 1]));
    }
    size_t off = (size_t)b * 524288 + (size_t)ks * 65536 + (size_t)cs * 4096
               + kh * 1024 + g * 512 + lane32 * 16;
    uint4 hv, lv;
    hv.x = h[0] | ((unsigned)h[1] << 16); hv.y = h[2] | ((unsigned)h[3] << 16);
    hv.z = h[4] | ((unsigned)h[5] << 16); hv.w = h[6] | ((unsigned)h[7] << 16);
    lv.x = lo8[0] | ((unsigned)lo8[1] << 16); lv.y = lo8[2] | ((unsigned)lo8[3] << 16);
    lv.z = lo8[4] | ((unsigned)lo8[5] << 16); lv.w = lo8[6] | ((unsigned)lo8[7] << 16);
    *(uint4*)(kps + off) = hv;               // hi plane
    *(uint4*)(kps + off + 2048) = lv;        // lo plane
}

// ---------------------------------------------------------------------------
// score kernel: 64 t x 512 l per block, 512 threads = 8 waves (wm2 x wn4).
// Swapped MFMA (A=KP rows l, B=Q cols t); lane owns row t = t0+wm*32+c31.
// Waves (0,wn),(1,wn) read the SAME K fragments -> B L2 traffic halves
// (1GB -> 512MB). LB(512,4): reg cap 128 (r9 lesson: (512,2) spilled).
// ---------------------------------------------------------------------------
__global__ __launch_bounds__(512, 4)
void score_kernel(const float* __restrict__ q,
                  const float* __restrict__ peq,
                  const char* __restrict__ kps,
                  const int* __restrict__ text_lengths,
                  const int* __restrict__ mel_lengths,
                  float* __restrict__ align_out,
                  int* __restrict__ idx_out,
                  int* __restrict__ flag_cnt,
                  int* __restrict__ flags) {
    __shared__ alignas(16) char smA[65536]; // [ks8][wm2][plane2][kh2][g2][r32][16B]
    struct Epi {
        float v1[2][4][32]; int i1[2][4][32]; float v2[2][4][32]; float S[2][4][32];
    };
    __shared__ Epi ep;
    float* smP = (float*)smA;               // epilogue: [64 rows][136] f32 (34.8KB)

    const int wgid = blockIdx.x;                 // 1024 blocks
    const int xcd = wgid & 7, loc = wgid >> 3;
    const int nid = xcd * 128 + loc;             // XCD-contiguous: 4 b's/XCD
    const int b  = nid >> 5;
    const int t0 = (nid & 31) << 6;              // 64-row tile

    const int tid = threadIdx.x;
    const int wid = tid >> 6, lane = tid & 63;
    const int wm = wid >> 2, wn = wid & 3;
    const int c31 = lane & 31, hi5 = lane >> 5;
    const int tlen = text_lengths[b];
    const int melq = mel_lengths[b] >> 2;

    const char* kpb = kps + (size_t)b * 524288 + (size_t)(hi5 * 512 + c31 * 16);

    f32x16 acc[4];
#pragma unroll
    for (int ci = 0; ci < 4; ++ci)
#pragma unroll
        for (int rg = 0; rg < 16; ++rg) acc[ci][rg] = 0.f;

#define BLOAD(dst, ksv, civ)                                                    \
    {                                                                           \
        const char* p_ = kpb + (ksv) * 65536 + (wn * 4 + (civ)) * 4096;         \
        (dst)[0] = *(const short8*)(p_);                                        \
        (dst)[1] = *(const short8*)(p_ + 1024);                                 \
        (dst)[2] = *(const short8*)(p_ + 2048);                                 \
        (dst)[3] = *(const short8*)(p_ + 3072);                                 \
    }
// swapped: A = K fragment (rows l), B = Q fragment (cols t)
#define MFMA6(CI, B)                                                            \
    {                                                                           \
        acc[CI] = __builtin_amdgcn_mfma_f32_32x32x16_bf16((B)[0], ah0, acc[CI], 0, 0, 0); \
        acc[CI] = __builtin_amdgcn_mfma_f32_32x32x16_bf16((B)[2], ah0, acc[CI], 0, 0, 0); \
        acc[CI] = __builtin_amdgcn_mfma_f32_32x32x16_bf16((B)[0], al0, acc[CI], 0, 0, 0); \
        acc[CI] = __builtin_amdgcn_mfma_f32_32x32x16_bf16((B)[1], ah1, acc[CI], 0, 0, 0); \
        acc[CI] = __builtin_amdgcn_mfma_f32_32x32x16_bf16((B)[3], ah1, acc[CI], 0, 0, 0); \
        acc[CI] = __builtin_amdgcn_mfma_f32_32x32x16_bf16((B)[1], al1, acc[CI], 0, 0, 0); \
    }

    short8 Bs[3][4];
    BLOAD(Bs[0], 0, 0)                           // phase 0
    BLOAD(Bs[1], 0, 1)                           // phase 1 (2-deep prologue)

    // ---- A staging: q+peq (64 rows) -> hi/lo fragment-order LDS (once) ----
    {
        const int sr = tid >> 3, kc = tid & 7;   // sr 0..63
        const float* qr = q   + ((size_t)(b * TDS) + t0 + sr) * DD;
        const float* pr = peq + (size_t)(t0 + sr) * DD;
#pragma unroll
        for (int kq = 0; kq < 4; ++kq) {
            int m = kq * 8 + kc;                 // 8-elem chunk index, k=m*8+j
            int k0 = m * 8;
            float4 qa = *(const float4*)(qr + k0);
            float4 qb4 = *(const float4*)(qr + k0 + 4);
            float4 pa = *(const float4*)(pr + k0);
            float4 pb = *(const float4*)(pr + k0 + 4);
            float e[8] = {(qa.x + pa.x) * 0.0625f, (qa.y + pa.y) * 0.0625f,
                          (qa.z + pa.z) * 0.0625f, (qa.w + pa.w) * 0.0625f,
                          (qb4.x + pb.x) * 0.0625f, (qb4.y + pb.y) * 0.0625f,
                          (qb4.z + pb.z) * 0.0625f, (qb4.w + pb.w) * 0.0625f};
            unsigned short h[8], lo[8];
#pragma unroll
            for (int j = 0; j < 8; ++j) {
                h[j] = f2bf(e[j]);
                lo[j] = f2bf(e[j] - bf2f(h[j]));
            }
            uint4 hv, lv;
            hv.x = h[0] | ((unsigned)h[1] << 16); hv.y = h[2] | ((unsigned)h[3] << 16);
            hv.z = h[4] | ((unsigned)h[5] << 16); hv.w = h[6] | ((unsigned)h[7] << 16);
            lv.x = lo[0] | ((unsigned)lo[1] << 16); lv.y = lo[2] | ((unsigned)lo[3] << 16);
            lv.z = lo[4] | ((unsigned)lo[5] << 16); lv.w = lo[6] | ((unsigned)lo[7] << 16);
            int base = (m >> 2) * 8192 + (sr >> 5) * 4096 + ((m >> 1) & 1) * 1024
                     + (m & 1) * 512 + (sr & 31) * 16;
            *(uint4*)(smA + base) = hv;          // plane 0 (hi)
            *(uint4*)(smA + base + 2048) = lv;   // plane 1 (lo)
        }
    }
    __syncthreads();

    const int afr = wm * 4096 + hi5 * 512 + c31 * 16;
    short8 ah0, ah1, al0, al1;
#pragma unroll
    for (int p = 0; p < 32; ++p) {               // phase p = (ks = p>>2, ci = p&3)
        if ((p & 3) == 0) {                      // new ks: read Q fragments
            const char* ab = smA + (p >> 2) * 8192 + afr;
            ah0 = *(const short8*)(ab);          // plane0 kh0
            ah1 = *(const short8*)(ab + 1024);   // plane0 kh1
            al0 = *(const short8*)(ab + 2048);   // plane1 kh0
            al1 = *(const short8*)(ab + 3072);   // plane1 kh1
        }
        if (p + 2 < 32) BLOAD(Bs[(p + 2) % 3], (p + 2) >> 2, (p + 2) & 3)
        MFMA6(p & 3, Bs[p % 3])
    }
#undef BLOAD
#undef MFMA6

    // ---- epilogue: lane owns row t = t0 + wm*32 + c31;
    //      acc[ci][rg] is col l = wn*128 + ci*32 + 4*hi5 + (rg&3) + 8*(rg>>2)
    const float NEGINF = -__builtin_inff();
    const int t = t0 + wm * 32 + c31;

    float v1 = NEGINF, v2 = NEGINF; int i1 = 0x7fffffff;
#pragma unroll
    for (int ci = 0; ci < 4; ++ci) {
        const int lbase = wn * 128 + ci * 32 + 4 * hi5;
#pragma unroll
        for (int rg = 0; rg < 16; ++rg) {
            int l = lbase + (rg & 3) + 8 * (rg >> 2);
            float v = acc[ci][rg];
            if (l >= tlen) { v = NEGINF; acc[ci][rg] = NEGINF; }
            if (v > v1)      { v2 = v1; v1 = v; i1 = l; }
            else if (v == v1) { i1 = min(i1, l); v2 = v1; }
            else if (v > v2) { v2 = v; }
        }
    }
    {
        float ov1 = __shfl_xor(v1, 32, 64);
        int   oi1 = __shfl_xor(i1, 32, 64);
        float ov2 = __shfl_xor(v2, 32, 64);
        if (ov1 > v1)      { v2 = fmaxf(v1, ov2); v1 = ov1; i1 = oi1; }
        else if (ov1 < v1) { v2 = fmaxf(v2, ov1); }
        else               { i1 = min(i1, oi1); v2 = v1; }
    }
    if (hi5 == 0) { ep.v1[wm][wn][c31] = v1; ep.i1[wm][wn][c31] = i1; ep.v2[wm][wn][c31] = v2; }
    __syncthreads();                 // also: all main-loop smA reads complete
    float V1 = ep.v1[wm][0][c31]; int I1 = ep.i1[wm][0][c31]; float V2 = ep.v2[wm][0][c31];
#pragma unroll
    for (int w = 1; w < 4; ++w) {
        float cv1 = ep.v1[wm][w][c31]; int ci1 = ep.i1[wm][w][c31]; float cv2 = ep.v2[wm][w][c31];
        if (cv1 > V1)      { V2 = fmaxf(V1, cv2); V1 = cv1; I1 = ci1; }
        else if (cv1 < V1) { V2 = fmaxf(V2, cv1); }
        else               { I1 = min(I1, ci1); V2 = V1; }
    }
    if (wn == 0 && hi5 == 0) {                   // one writer per t
        idx_out[b * TDS + t] = I1;
        if (t < melq && (V1 - V2) < GAP_THR) {
            int pos = atomicAdd(flag_cnt, 1);
            flags[pos] = (b << 11) | t;
        }
    }
    // softmax
    float s = 0.f;
#pragma unroll
    for (int ci = 0; ci < 4; ++ci)
#pragma unroll
        for (int rg = 0; rg < 16; ++rg) {
            float p = __expf(acc[ci][rg] - V1);
            acc[ci][rg] = p; s += p;
        }
    s += __shfl_xor(s, 32, 64);
    if (hi5 == 0) ep.S[wm][wn][c31] = s;
    __syncthreads();
    float denom = ep.S[wm][0][c31] + ep.S[wm][1][c31] + ep.S[wm][2][c31] + ep.S[wm][3][c31];
    const float sc = (t < melq) ? (1.0f / denom) : 0.f;

    // ---- coalesced align stores via LDS transpose (4 per-ci passes) ----
    const int STRIDE = 136;                      // f32; 2-way bank conflict max
    const int su = tid & 7;                      // 8 threads x f32x4 = 32 cols
    const int swn = (tid >> 3) & 3;              // wn group of cols
    const int sr0 = tid >> 5;                    // base row 0..15
    const int prow = wm * 32 + c31;              // lane's P row (0..63)
#pragma unroll
    for (int ci = 0; ci < 4; ++ci) {
#pragma unroll
        for (int rh = 0; rh < 4; ++rh) {
            f32x4 o = {acc[ci][rh * 4 + 0] * sc, acc[ci][rh * 4 + 1] * sc,
                       acc[ci][rh * 4 + 2] * sc, acc[ci][rh * 4 + 3] * sc};
            *(f32x4*)(smP + prow * STRIDE + wn * 32 + 4 * hi5 + 8 * rh) = o;
        }
        __syncthreads();
#pragma unroll
        for (int rr = 0; rr < 4; ++rr) {
            int row = sr0 + 16 * rr;
            f32x4 o = *(const f32x4*)(smP + row * STRIDE + swn * 32 + su * 4);
            size_t goff = ((size_t)(b * TDS + t0 + row)) * LL
                        + swn * 128 + ci * 32 + su * 4;
            __builtin_nontemporal_store(o, (f32x4*)(align_out + goff));
        }
        __syncthreads();
    }
}

// ---------------------------------------------------------------------------
// refine kernel v2: recompute flagged rows' scores with f64 dot + range-
// reduced sincosf PE (abs err ~1e-7).
// ---------------------------------------------------------------------------
__global__ __launch_bounds__(256)
void refine_kernel(const float* __restrict__ q,
                   const float* __restrict__ k,
                   const int* __restrict__ text_lengths,
                   const int* __restrict__ mel_lengths,
                   const int* __restrict__ flags,
                   const int* __restrict__ flag_cnt,
                   int* __restrict__ idx_out) {
    __shared__ double qd[DD];
    __shared__ double invdiv[128];
    __shared__ double rbest[4];
    __shared__ int    ribest[4];
    const int tid = threadIdx.x;
    if (tid < 128)
        invdiv[tid] = 1.0 / pow(10000.0, (double)tid * (1.0 / 128.0));
    const int cnt = flag_cnt[0];
    for (int r = blockIdx.x; r < cnt; r += gridDim.x) {
        const int code = flags[r];
        const int b = code >> 11, t = code & 2047;
        const int tlen = text_lengths[b];
        const double ws = ((double)mel_lengths[b] * 0.25) / (double)text_lengths[b];
        __syncthreads();
        {
            const int d = tid, i = d >> 1;
            float sn, cs;
            rr_sincosf((double)t * invdiv[i], &sn, &cs);
            qd[d] = ((double)q[((size_t)b * TDS + t) * DD + d]
                     + (double)((d & 1) ? cs : sn)) * 0.0625;
        }
        __syncthreads();
        double best = -1.0e300; int bi = 0x7fffffff;
        for (int p = 0; p < 2; ++p) {
            const int l = tid + p * 256;
            if (l < tlen) {
                const float* kr = k + ((size_t)b * LL + l) * DD;
                const double wl = ws * (double)l;
                double sacc = 0.0;
                for (int i = 0; i < 128; ++i) {
                    float sn, cs;
                    rr_sincosf(wl * invdiv[i], &sn, &cs);
                    sacc += ((double)kr[2 * i]     + (double)sn) * qd[2 * i];
                    sacc += ((double)kr[2 * i + 1] + (double)cs) * qd[2 * i + 1];
                }
                if (sacc > best || (sacc == best && l < bi)) { best = sacc; bi = l; }
            }
        }
        for (int off = 1; off <= 32; off <<= 1) {
            double ov = __shfl_xor(best, off, 64);
            int   oi = __shfl_xor(bi, off, 64);
            if (ov > best || (ov == best && oi < bi)) { best = ov; bi = oi; }
        }
        const int wv = tid >> 6;
        if ((tid & 63) == 0) { rbest[wv] = best; ribest[wv] = bi; }
        __syncthreads();
        if (tid == 0) {
            double bb = rbest[0]; int ii = ribest[0];
            for (int w = 1; w < 4; ++w)
                if (rbest[w] > bb || (rbest[w] == bb && ribest[w] < ii)) { bb = rbest[w]; ii = ribest[w]; }
            idx_out[b * TDS + t] = ii;
        }
    }
}

// ---------------------------------------------------------------------------
// compress kernel v2: 64-t tiles, per-ks W/V staging (small LDS, 4+ blocks/CU)
// out[b,c,t] = sum_d w[c,d] * v[b, idx[b,t], d] (0 if masked)
// ---------------------------------------------------------------------------
__global__ __launch_bounds__(256)
void compress_kernel(const float* __restrict__ v,
                     const float* __restrict__ wc,
                     const int* __restrict__ idx_in,
                     const int* __restrict__ mel_lengths,
                     float* __restrict__ out) {
    __shared__ float Ws[16 * 68];   // [kk][c]
    __shared__ float Vs[16 * 68];   // [kk][t]
    __shared__ int   idxs[64];
    const int b   = blockIdx.y;
    const int t0  = blockIdx.x * 64;
    const int tid = threadIdx.x;
    const int melq = mel_lengths[b] >> 2;
    const float* vb = v + (size_t)b * LL * DD;

    if (tid < 64) {
        int t = t0 + tid;
        int ii = idx_in[b * TDS + t];
        idxs[tid] = (t >= melq) ? -1 : ii;
    }

    const int tx = tid >> 5;       // c-group 0..7 (8 c each)
    const int ty = tid & 31;       // t-group 0..31 (2 t each)
    const int sc = tid >> 2;       // staging c or t: 0..63
    const int su = tid & 3;        // staging d-chunk
    float acc[8][2];
#pragma unroll
    for (int i = 0; i < 8; ++i) { acc[i][0] = 0.f; acc[i][1] = 0.f; }

    for (int ks = 0; ks < 16; ++ks) {
        const int d0 = ks * 16;
        __syncthreads();   // protect Ws/Vs (and idxs on first iter)
        {
            float4 wv = *(const float4*)(wc + (size_t)sc * DD + d0 + su * 4);
            Ws[(su * 4 + 0) * 68 + sc] = wv.x;
            Ws[(su * 4 + 1) * 68 + sc] = wv.y;
            Ws[(su * 4 + 2) * 68 + sc] = wv.z;
            Ws[(su * 4 + 3) * 68 + sc] = wv.w;
            int row = idxs[sc];
            float4 vv = make_float4(0.f, 0.f, 0.f, 0.f);
            if (row >= 0) vv = *(const float4*)(vb + (size_t)row * DD + d0 + su * 4);
            Vs[(su * 4 + 0) * 68 + sc] = vv.x;
            Vs[(su * 4 + 1) * 68 + sc] = vv.y;
            Vs[(su * 4 + 2) * 68 + sc] = vv.z;
            Vs[(su * 4 + 3) * 68 + sc] = vv.w;
        }
        __syncthreads();
#pragma unroll
        for (int kk = 0; kk < 16; ++kk) {
            const float* wrow = Ws + kk * 68 + tx * 8;
            float4 a0 = *(const float4*)(wrow);
            float4 a1 = *(const float4*)(wrow + 4);
            float2 bb = *(const float2*)(Vs + kk * 68 + ty * 2);
            const float av[8] = {a0.x, a0.y, a0.z, a0.w, a1.x, a1.y, a1.z, a1.w};
#pragma unroll
            for (int i = 0; i < 8; ++i) {
                acc[i][0] = fmaf(av[i], bb.x, acc[i][0]);
                acc[i][1] = fmaf(av[i], bb.y, acc[i][1]);
            }
        }
    }
#pragma unroll
    for (int i = 0; i < 8; ++i) {
        int c = tx * 8 + i;
        float2 o = make_float2(acc[i][0], acc[i][1]);
        *(float2*)(out + ((size_t)(b * DC + c)) * TDS + t0 + ty * 2) = o;
    }
}

extern "C" void kernel_launch(void* const* d_in, const int* in_sizes, int n_in,
                              void* d_out, int out_size, void* d_ws, size_t ws_size,
                              hipStream_t stream) {
    const float* q    = (const float*)d_in[0];
    const float* k    = (const float*)d_in[1];
    const float* v    = (const float*)d_in[2];
    const float* wc   = (const float*)d_in[3];
    const int*   text = (const int*)d_in[4];
    const int*   mel  = (const int*)d_in[5];

    float* out   = (float*)d_out;
    float* align = out + (size_t)NB * DC * TDS;

    char*  wsb = (char*)d_ws;
    char*  KPS = wsb;
    float* PEQ = (float*)(wsb + 16777216);
    int*   IDX = (int*)(wsb + 16777216 + 2097152);
    int*   CNT = IDX + (size_t)NB * TDS;
    int*   FLG = CNT + 1;

    hipLaunchKernelGGL(tables_kernel, dim3(4096), dim3(256), 0, stream,
                       k, text, mel, PEQ, KPS, CNT);
    hipLaunchKernelGGL(score_kernel, dim3(1024), dim3(512), 0, stream,
                       q, PEQ, KPS, text, mel, align, IDX, CNT, FLG);
    hipLaunchKernelGGL(refine_kernel, dim3(256), dim3(256), 0, stream,
                       q, k, text, mel, FLG, CNT, IDX);
    hipLaunchKernelGGL(compress_kernel, dim3(TDS / 64, NB), dim3(256), 0, stream,
                       v, wc, IDX, mel, out);
}

// Round 16
// 192.397 us; speedup vs baseline: 1.1077x; 1.1077x over previous
//
#include <hip/hip_runtime.h>
#include <math.h>

#define NB  32
#define TDS 2048
#define LL  512
#define DD  256
#define DC  64   // D/RATIO
#define GAP_THR 4e-4f

typedef __attribute__((ext_vector_type(8)))  short short8;
typedef __attribute__((ext_vector_type(16))) float f32x16;
typedef __attribute__((ext_vector_type(4)))  float f32x4;

__device__ __forceinline__ unsigned short f2bf(float x) {
    union { float f; unsigned u; } v; v.f = x;
    unsigned r = v.u + 0x7fffu + ((v.u >> 16) & 1u);
    return (unsigned short)(r >> 16);
}
__device__ __forceinline__ float bf2f(unsigned short h) {
    union { unsigned u; float f; } v; v.u = ((unsigned)h) << 16;
    return v.f;
}
// range-reduced sincos: f64 reduction to [-pi,pi], f32 evaluation (~1e-7 abs err)
__device__ __forceinline__ void rr_sincosf(double ang, float* s, float* c) {
    double n = rint(ang * 0.15915494309189535);
    double red = fma(n, -6.283185307179586, ang);
    sincosf((float)red, s, c);
}

// ---------------------------------------------------------------------------
// ws layout (bytes):
//   [0, 16777216)           : KPS  bf16 hi+lo of k+pe_k, MFMA-fragment order
//   [16777216, 18874368)    : PEQ  f32 (pe_q with w_s=1)
//   then NB*TDS ints IDX, 1 int CNT, NB*TDS ints FLAGS
// KPS fragment order: element (b, l=cs*32+lane32, k=ks*32+kh*16+g*8+j, plane):
//   byte = b*524288 + ks*65536 + cs*4096 + plane*2048 + kh*1024 + g*512
//        + lane32*16 + j*2
// ---------------------------------------------------------------------------

// merged table builder: blocks [0,2048) build PEQ (+cnt init);
// blocks [2048,4096) build the KPS fragment image.
__global__ __launch_bounds__(256)
void tables_kernel(const float* __restrict__ k,
                   const int* __restrict__ text_lengths,
                   const int* __restrict__ mel_lengths,
                   float* __restrict__ peq,
                   char* __restrict__ kps,
                   int* __restrict__ cnt) {
    const int tid = threadIdx.x;
    if (blockIdx.x < 2048) {
        int idx = blockIdx.x * 256 + tid;            // < TDS*DD
        if (idx == 0) cnt[0] = 0;
        int t = idx >> 8;
        int d = idx & 255;
        int i = d >> 1;
        double invd = exp((double)i * (-9.210340371976184 / 128.0));
        double ang = (double)t * invd;
        double s, c;
        sincos(ang, &s, &c);
        peq[idx] = (float)((d & 1) ? c : s);
        return;
    }
    __shared__ double invdiv[128];
    if (tid < 128) invdiv[tid] = exp((double)tid * (-9.210340371976184 / 128.0));
    __syncthreads();
    int f = (blockIdx.x - 2048) * 256 + tid;         // < NB*16384
    int b = f >> 14;
    int r = f & 16383;
    int ks = r >> 11;                                // 0..7
    int r2 = r & 2047;
    int cs = r2 >> 7;                                // 0..15
    int r3 = r2 & 127;
    int kh = r3 >> 6;
    int g  = (r3 >> 5) & 1;
    int lane32 = r3 & 31;
    int l  = cs * 32 + lane32;
    int k0 = ks * 32 + kh * 16 + g * 8;
    const float* kr = k + ((size_t)(b * LL + l)) * DD + k0;
    float4 kv0 = *(const float4*)(kr);
    float4 kv1 = *(const float4*)(kr + 4);
    float kv[8] = {kv0.x, kv0.y, kv0.z, kv0.w, kv1.x, kv1.y, kv1.z, kv1.w};
    double wsd = ((double)mel_lengths[b] * 0.25) / (double)text_lengths[b];
    double base_ang = wsd * (double)l;
    unsigned short h[8], lo8[8];
#pragma unroll
    for (int jj = 0; jj < 4; ++jj) {
        int i = (k0 >> 1) + jj;
        float sn, cs2;
        rr_sincosf(base_ang * invdiv[i], &sn, &cs2);
        float e0 = kv[2 * jj] + sn;
        float e1 = kv[2 * jj + 1] + cs2;
        h[2 * jj]       = f2bf(e0);
        h[2 * jj + 1]   = f2bf(e1);
        lo8[2 * jj]     = f2bf(e0 - bf2f(h[2 * jj]));
        lo8[2 * jj + 1] = f2bf(e1 - bf2f(h[2 * jj + 1]));
    }
    size_t off = (size_t)b * 524288 + (size_t)ks * 65536 + (size_t)cs * 4096
               + kh * 1024 + g * 512 + lane32 * 16;
    uint4 hv, lv;
    hv.x = h[0] | ((unsigned)h[1] << 16); hv.y = h[2] | ((unsigned)h[3] << 16);
    hv.z = h[4] | ((unsigned)h[5] << 16); hv.w = h[6] | ((unsigned)h[7] << 16);
    lv.x = lo8[0] | ((unsigned)lo8[1] << 16); lv.y = lo8[2] | ((unsigned)lo8[3] << 16);
    lv.z = lo8[4] | ((unsigned)lo8[5] << 16); lv.w = lo8[6] | ((unsigned)lo8[7] << 16);
    *(uint4*)(kps + off) = hv;               // hi plane
    *(uint4*)(kps + off + 2048) = lv;        // lo plane
}

// ---------------------------------------------------------------------------
// score kernel: 32 t x 512 l per block, 256 threads = 4 waves (r14 config,
// best measured). Swapped MFMA (A=KP rows l, B=Q cols t); lane owns one row.
// + s_setprio around MFMA cluster (T5: helps free-running multi-wave loops).
// ---------------------------------------------------------------------------
__global__ __launch_bounds__(256, 3)
void score_kernel(const float* __restrict__ q,
                  const float* __restrict__ peq,
                  const char* __restrict__ kps,
                  const int* __restrict__ text_lengths,
                  const int* __restrict__ mel_lengths,
                  float* __restrict__ align_out,
                  int* __restrict__ idx_out,
                  int* __restrict__ flag_cnt,
                  int* __restrict__ flags) {
    __shared__ alignas(16) char smA[32768];  // Q frags; reused as P-store tile
    struct Epi {
        float v1[4][32]; int i1[4][32]; float v2[4][32]; float S[4][32];
    };
    __shared__ Epi ep;
    float* smP = (float*)smA;                // [32 rows][136 stride] f32

    const int wgid = blockIdx.x;                 // 2048 blocks
    const int xcd = wgid & 7, loc = wgid >> 3;
    const int nid = xcd * 256 + loc;             // XCD-contiguous: 4 b's/XCD
    const int b  = nid >> 6;
    const int t0 = (nid & 63) << 5;              // 32-row tile

    const int tid = threadIdx.x;
    const int wn = tid >> 6, lane = tid & 63;
    const int c31 = lane & 31, hi5 = lane >> 5;
    const int tlen = text_lengths[b];
    const int melq = mel_lengths[b] >> 2;

    const char* kpb = kps + (size_t)b * 524288 + (size_t)(hi5 * 512 + c31 * 16);

    f32x16 acc[4];
#pragma unroll
    for (int ci = 0; ci < 4; ++ci)
#pragma unroll
        for (int rg = 0; rg < 16; ++rg) acc[ci][rg] = 0.f;

#define BLOAD(dst, ksv, civ)                                                    \
    {                                                                           \
        const char* p_ = kpb + (ksv) * 65536 + (wn * 4 + (civ)) * 4096;         \
        (dst)[0] = *(const short8*)(p_);                                        \
        (dst)[1] = *(const short8*)(p_ + 1024);                                 \
        (dst)[2] = *(const short8*)(p_ + 2048);                                 \
        (dst)[3] = *(const short8*)(p_ + 3072);                                 \
    }
// swapped: A = K fragment (rows l), B = Q fragment (cols t)
#define MFMA6(CI, B)                                                            \
    {                                                                           \
        __builtin_amdgcn_s_setprio(1);                                          \
        acc[CI] = __builtin_amdgcn_mfma_f32_32x32x16_bf16((B)[0], ah0, acc[CI], 0, 0, 0); \
        acc[CI] = __builtin_amdgcn_mfma_f32_32x32x16_bf16((B)[2], ah0, acc[CI], 0, 0, 0); \
        acc[CI] = __builtin_amdgcn_mfma_f32_32x32x16_bf16((B)[0], al0, acc[CI], 0, 0, 0); \
        acc[CI] = __builtin_amdgcn_mfma_f32_32x32x16_bf16((B)[1], ah1, acc[CI], 0, 0, 0); \
        acc[CI] = __builtin_amdgcn_mfma_f32_32x32x16_bf16((B)[3], ah1, acc[CI], 0, 0, 0); \
        acc[CI] = __builtin_amdgcn_mfma_f32_32x32x16_bf16((B)[1], al1, acc[CI], 0, 0, 0); \
        __builtin_amdgcn_s_setprio(0);                                          \
    }

    short8 Bs[3][4];
    BLOAD(Bs[0], 0, 0)                           // phase 0
    BLOAD(Bs[1], 0, 1)                           // phase 1 (2-deep prologue)

    // ---- A staging: q+peq -> hi/lo fragment-order LDS (once) ----
    {
        const int sr = tid >> 3, kc = tid & 7;
        const float* qr = q   + ((size_t)(b * TDS) + t0 + sr) * DD;
        const float* pr = peq + (size_t)(t0 + sr) * DD;
#pragma unroll
        for (int kq = 0; kq < 4; ++kq) {
            int m = kq * 8 + kc;                 // 8-elem chunk index, k=m*8+j
            int k0 = m * 8;
            float4 qa = *(const float4*)(qr + k0);
            float4 qb4 = *(const float4*)(qr + k0 + 4);
            float4 pa = *(const float4*)(pr + k0);
            float4 pb = *(const float4*)(pr + k0 + 4);
            float e[8] = {(qa.x + pa.x) * 0.0625f, (qa.y + pa.y) * 0.0625f,
                          (qa.z + pa.z) * 0.0625f, (qa.w + pa.w) * 0.0625f,
                          (qb4.x + pb.x) * 0.0625f, (qb4.y + pb.y) * 0.0625f,
                          (qb4.z + pb.z) * 0.0625f, (qb4.w + pb.w) * 0.0625f};
            unsigned short h[8], lo[8];
#pragma unroll
            for (int j = 0; j < 8; ++j) {
                h[j] = f2bf(e[j]);
                lo[j] = f2bf(e[j] - bf2f(h[j]));
            }
            uint4 hv, lv;
            hv.x = h[0] | ((unsigned)h[1] << 16); hv.y = h[2] | ((unsigned)h[3] << 16);
            hv.z = h[4] | ((unsigned)h[5] << 16); hv.w = h[6] | ((unsigned)h[7] << 16);
            lv.x = lo[0] | ((unsigned)lo[1] << 16); lv.y = lo[2] | ((unsigned)lo[3] << 16);
            lv.z = lo[4] | ((unsigned)lo[5] << 16); lv.w = lo[6] | ((unsigned)lo[7] << 16);
            int base = (m >> 2) * 4096 + ((m >> 1) & 1) * 1024 + (m & 1) * 512 + sr * 16;
            *(uint4*)(smA + base) = hv;          // plane 0 (hi)
            *(uint4*)(smA + base + 2048) = lv;   // plane 1 (lo)
        }
    }
    __syncthreads();

    const int afr = hi5 * 512 + c31 * 16;
    short8 ah0, ah1, al0, al1;
#pragma unroll
    for (int p = 0; p < 32; ++p) {               // phase p = (ks = p>>2, ci = p&3)
        if ((p & 3) == 0) {                      // new ks: read Q fragments
            const char* ab = smA + (p >> 2) * 4096 + afr;
            ah0 = *(const short8*)(ab);          // plane0 kh0
            ah1 = *(const short8*)(ab + 1024);   // plane0 kh1
            al0 = *(const short8*)(ab + 2048);   // plane1 kh0
            al1 = *(const short8*)(ab + 3072);   // plane1 kh1
        }
        if (p + 2 < 32) BLOAD(Bs[(p + 2) % 3], (p + 2) >> 2, (p + 2) & 3)
        MFMA6(p & 3, Bs[p % 3])
    }
#undef BLOAD
#undef MFMA6

    // ---- epilogue (transposed C): lane owns row t = t0 + c31;
    //      acc[ci][rg] is col l = wn*128 + ci*32 + 4*hi5 + (rg&3) + 8*(rg>>2)
    const float NEGINF = -__builtin_inff();
    const int t = t0 + c31;

    float v1 = NEGINF, v2 = NEGINF; int i1 = 0x7fffffff;
#pragma unroll
    for (int ci = 0; ci < 4; ++ci) {
        const int lbase = wn * 128 + ci * 32 + 4 * hi5;
#pragma unroll
        for (int rg = 0; rg < 16; ++rg) {
            int l = lbase + (rg & 3) + 8 * (rg >> 2);
            float v = acc[ci][rg];
            if (l >= tlen) { v = NEGINF; acc[ci][rg] = NEGINF; }
            if (v > v1)      { v2 = v1; v1 = v; i1 = l; }
            else if (v == v1) { i1 = min(i1, l); v2 = v1; }
            else if (v > v2) { v2 = v; }
        }
    }
    {
        float ov1 = __shfl_xor(v1, 32, 64);
        int   oi1 = __shfl_xor(i1, 32, 64);
        float ov2 = __shfl_xor(v2, 32, 64);
        if (ov1 > v1)      { v2 = fmaxf(v1, ov2); v1 = ov1; i1 = oi1; }
        else if (ov1 < v1) { v2 = fmaxf(v2, ov1); }
        else               { i1 = min(i1, oi1); v2 = v1; }
    }
    if (hi5 == 0) { ep.v1[wn][c31] = v1; ep.i1[wn][c31] = i1; ep.v2[wn][c31] = v2; }
    __syncthreads();                 // also: all main-loop smA reads complete
    float V1 = ep.v1[0][c31]; int I1 = ep.i1[0][c31]; float V2 = ep.v2[0][c31];
#pragma unroll
    for (int w = 1; w < 4; ++w) {
        float cv1 = ep.v1[w][c31]; int ci1 = ep.i1[w][c31]; float cv2 = ep.v2[w][c31];
        if (cv1 > V1)      { V2 = fmaxf(V1, cv2); V1 = cv1; I1 = ci1; }
        else if (cv1 < V1) { V2 = fmaxf(V2, cv1); }
        else               { I1 = min(I1, ci1); V2 = V1; }
    }
    if (tid < 32) {                              // one writer per t
        idx_out[b * TDS + t] = I1;
        if (t < melq && (V1 - V2) < GAP_THR) {
            int pos = atomicAdd(flag_cnt, 1);
            flags[pos] = (b << 11) | t;
        }
    }
    // softmax: p = exp(s - V1), per-lane sum
    float s = 0.f;
#pragma unroll
    for (int ci = 0; ci < 4; ++ci)
#pragma unroll
        for (int rg = 0; rg < 16; ++rg) {
            float p = __expf(acc[ci][rg] - V1);
            acc[ci][rg] = p; s += p;
        }
    s += __shfl_xor(s, 32, 64);
    if (hi5 == 0) ep.S[wn][c31] = s;
    __syncthreads();
    float denom = ep.S[0][c31] + ep.S[1][c31] + ep.S[2][c31] + ep.S[3][c31];
    const float sc = (t < melq) ? (1.0f / denom) : 0.f;

    // ---- coalesced align stores via LDS transpose (4 per-ci passes) ----
    const int STRIDE = 136;                      // f32; 2-way bank conflict max
    const int su = tid & 7;                      // 8 threads x f32x4 = 32 cols
    const int swn = (tid >> 3) & 3;              // wn group of cols
    const int sr0 = tid >> 5;                    // base row 0..7
#pragma unroll
    for (int ci = 0; ci < 4; ++ci) {
#pragma unroll
        for (int rh = 0; rh < 4; ++rh) {
            f32x4 o = {acc[ci][rh * 4 + 0] * sc, acc[ci][rh * 4 + 1] * sc,
                       acc[ci][rh * 4 + 2] * sc, acc[ci][rh * 4 + 3] * sc};
            *(f32x4*)(smP + c31 * STRIDE + wn * 32 + 4 * hi5 + 8 * rh) = o;
        }
        __syncthreads();
#pragma unroll
        for (int rr = 0; rr < 4; ++rr) {
            int row = sr0 + 8 * rr;
            f32x4 o = *(const f32x4*)(smP + row * STRIDE + swn * 32 + su * 4);
            size_t goff = ((size_t)(b * TDS + t0 + row)) * LL
                        + swn * 128 + ci * 32 + su * 4;
            __builtin_nontemporal_store(o, (f32x4*)(align_out + goff));
        }
        __syncthreads();
    }
}

// ---------------------------------------------------------------------------
// refine kernel v2: recompute flagged rows' scores with f64 dot + range-
// reduced sincosf PE (abs err ~1e-7).
// ---------------------------------------------------------------------------
__global__ __launch_bounds__(256)
void refine_kernel(const float* __restrict__ q,
                   const float* __restrict__ k,
                   const int* __restrict__ text_lengths,
                   const int* __restrict__ mel_lengths,
                   const int* __restrict__ flags,
                   const int* __restrict__ flag_cnt,
                   int* __restrict__ idx_out) {
    __shared__ double qd[DD];
    __shared__ double invdiv[128];
    __shared__ double rbest[4];
    __shared__ int    ribest[4];
    const int tid = threadIdx.x;
    if (tid < 128)
        invdiv[tid] = 1.0 / pow(10000.0, (double)tid * (1.0 / 128.0));
    const int cnt = flag_cnt[0];
    for (int r = blockIdx.x; r < cnt; r += gridDim.x) {
        const int code = flags[r];
        const int b = code >> 11, t = code & 2047;
        const int tlen = text_lengths[b];
        const double ws = ((double)mel_lengths[b] * 0.25) / (double)text_lengths[b];
        __syncthreads();
        {
            const int d = tid, i = d >> 1;
            float sn, cs;
            rr_sincosf((double)t * invdiv[i], &sn, &cs);
            qd[d] = ((double)q[((size_t)b * TDS + t) * DD + d]
                     + (double)((d & 1) ? cs : sn)) * 0.0625;
        }
        __syncthreads();
        double best = -1.0e300; int bi = 0x7fffffff;
        for (int p = 0; p < 2; ++p) {
            const int l = tid + p * 256;
            if (l < tlen) {
                const float* kr = k + ((size_t)b * LL + l) * DD;
                const double wl = ws * (double)l;
                double sacc = 0.0;
                for (int i = 0; i < 128; ++i) {
                    float sn, cs;
                    rr_sincosf(wl * invdiv[i], &sn, &cs);
                    sacc += ((double)kr[2 * i]     + (double)sn) * qd[2 * i];
                    sacc += ((double)kr[2 * i + 1] + (double)cs) * qd[2 * i + 1];
                }
                if (sacc > best || (sacc == best && l < bi)) { best = sacc; bi = l; }
            }
        }
        for (int off = 1; off <= 32; off <<= 1) {
            double ov = __shfl_xor(best, off, 64);
            int   oi = __shfl_xor(bi, off, 64);
            if (ov > best || (ov == best && oi < bi)) { best = ov; bi = oi; }
        }
        const int wv = tid >> 6;
        if ((tid & 63) == 0) { rbest[wv] = best; ribest[wv] = bi; }
        __syncthreads();
        if (tid == 0) {
            double bb = rbest[0]; int ii = ribest[0];
            for (int w = 1; w < 4; ++w)
                if (rbest[w] > bb || (rbest[w] == bb && ribest[w] < ii)) { bb = rbest[w]; ii = ribest[w]; }
            idx_out[b * TDS + t] = ii;
        }
    }
}

// ---------------------------------------------------------------------------
// compress kernel v2: 64-t tiles, per-ks W/V staging (small LDS, 4+ blocks/CU)
// out[b,c,t] = sum_d w[c,d] * v[b, idx[b,t], d] (0 if masked)
// ---------------------------------------------------------------------------
__global__ __launch_bounds__(256)
void compress_kernel(const float* __restrict__ v,
                     const float* __restrict__ wc,
                     const int* __restrict__ idx_in,
                     const int* __restrict__ mel_lengths,
                     float* __restrict__ out) {
    __shared__ float Ws[16 * 68];   // [kk][c]
    __shared__ float Vs[16 * 68];   // [kk][t]
    __shared__ int   idxs[64];
    const int b   = blockIdx.y;
    const int t0  = blockIdx.x * 64;
    const int tid = threadIdx.x;
    const int melq = mel_lengths[b] >> 2;
    const float* vb = v + (size_t)b * LL * DD;

    if (tid < 64) {
        int t = t0 + tid;
        int ii = idx_in[b * TDS + t];
        idxs[tid] = (t >= melq) ? -1 : ii;
    }

    const int tx = tid >> 5;       // c-group 0..7 (8 c each)
    const int ty = tid & 31;       // t-group 0..31 (2 t each)
    const int sc = tid >> 2;       // staging c or t: 0..63
    const int su = tid & 3;        // staging d-chunk
    float acc[8][2];
#pragma unroll
    for (int i = 0; i < 8; ++i) { acc[i][0] = 0.f; acc[i][1] = 0.f; }

    for (int ks = 0; ks < 16; ++ks) {
        const int d0 = ks * 16;
        __syncthreads();   // protect Ws/Vs (and idxs on first iter)
        {
            float4 wv = *(const float4*)(wc + (size_t)sc * DD + d0 + su * 4);
            Ws[(su * 4 + 0) * 68 + sc] = wv.x;
            Ws[(su * 4 + 1) * 68 + sc] = wv.y;
            Ws[(su * 4 + 2) * 68 + sc] = wv.z;
            Ws[(su * 4 + 3) * 68 + sc] = wv.w;
            int row = idxs[sc];
            float4 vv = make_float4(0.f, 0.f, 0.f, 0.f);
            if (row >= 0) vv = *(const float4*)(vb + (size_t)row * DD + d0 + su * 4);
            Vs[(su * 4 + 0) * 68 + sc] = vv.x;
            Vs[(su * 4 + 1) * 68 + sc] = vv.y;
            Vs[(su * 4 + 2) * 68 + sc] = vv.z;
            Vs[(su * 4 + 3) * 68 + sc] = vv.w;
        }
        __syncthreads();
#pragma unroll
        for (int kk = 0; kk < 16; ++kk) {
            const float* wrow = Ws + kk * 68 + tx * 8;
            float4 a0 = *(const float4*)(wrow);
            float4 a1 = *(const float4*)(wrow + 4);
            float2 bb = *(const float2*)(Vs + kk * 68 + ty * 2);
            const float av[8] = {a0.x, a0.y, a0.z, a0.w, a1.x, a1.y, a1.z, a1.w};
#pragma unroll
            for (int i = 0; i < 8; ++i) {
                acc[i][0] = fmaf(av[i], bb.x, acc[i][0]);
                acc[i][1] = fmaf(av[i], bb.y, acc[i][1]);
            }
        }
    }
#pragma unroll
    for (int i = 0; i < 8; ++i) {
        int c = tx * 8 + i;
        float2 o = make_float2(acc[i][0], acc[i][1]);
        *(float2*)(out + ((size_t)(b * DC + c)) * TDS + t0 + ty * 2) = o;
    }
}

extern "C" void kernel_launch(void* const* d_in, const int* in_sizes, int n_in,
                              void* d_out, int out_size, void* d_ws, size_t ws_size,
                              hipStream_t stream) {
    const float* q    = (const float*)d_in[0];
    const float* k    = (const float*)d_in[1];
    const float* v    = (const float*)d_in[2];
    const float* wc   = (const float*)d_in[3];
    const int*   text = (const int*)d_in[4];
    const int*   mel  = (const int*)d_in[5];

    float* out   = (float*)d_out;
    float* align = out + (size_t)NB * DC * TDS;

    char*  wsb = (char*)d_ws;
    char*  KPS = wsb;
    float* PEQ = (float*)(wsb + 16777216);
    int*   IDX = (int*)(wsb + 16777216 + 2097152);
    int*   CNT = IDX + (size_t)NB * TDS;
    int*   FLG = CNT + 1;

    hipLaunchKernelGGL(tables_kernel, dim3(4096), dim3(256), 0, stream,
                       k, text, mel, PEQ, KPS, CNT);
    hipLaunchKernelGGL(score_kernel, dim3(2048), dim3(256), 0, stream,
                       q, PEQ, KPS, text, mel, align, IDX, CNT, FLG);
    hipLaunchKernelGGL(refine_kernel, dim3(256), dim3(256), 0, stream,
                       q, k, text, mel, FLG, CNT, IDX);
    hipLaunchKernelGGL(compress_kernel, dim3(TDS / 64, NB), dim3(256), 0, stream,
                       v, wc, IDX, mel, out);
}